// Round 9
// baseline (125.453 us; speedup 1.0000x reference)
//
#include <hip/hip_runtime.h>

#define WIDTH  262144
#define OUTW   (WIDTH - 31)         // 262113
#define WTILE  512                  // outputs per wave
#define NSW    560                  // staged elements per wave (512 + 48 halo)
#define SCALE_V 0.17782794100389229f // sqrt(10^(-15/10))
#define LOG2E_X2 2.8853900817779268f // 2*log2(e)

#define TBL_N    1024
#define TBL_MAX  10.0f
#define TBL_SCL  (TBL_N / TBL_MAX)   // 102.4

typedef _Float16 half8  __attribute__((ext_vector_type(8)));
typedef _Float16 half4v __attribute__((ext_vector_type(4)));
typedef float    floatx4 __attribute__((ext_vector_type(4)));

#define MFMA16(A, B, C) __builtin_amdgcn_mfma_f32_16x16x32_f16((A), (B), (C), 0, 0, 0)

// s(mag) = sum_f w2[f]*tanh(w1[f]*mag)/mag  (even, smooth; s(0)=sum w2*w1)
__device__ __forceinline__ float s_of_mag(float mag, const float* w1, const float* w2) {
    if (mag == 0.0f) {
        float s = 0.f;
#pragma unroll
        for (int f = 0; f < 8; ++f) s = fmaf(w2[f], w1[f], s);   // tanh'(0)=1
        return s;
    }
    float m = 0.f;
#pragma unroll
    for (int f = 0; f < 8; ++f) {
        const float e2 = __builtin_amdgcn_exp2f(LOG2E_X2 * w1[f] * mag);
        const float th = 1.0f - 2.0f * __builtin_amdgcn_rcpf(e2 + 1.0f);
        m = fmaf(w2[f], th, m);
    }
    return m / mag;
}

// Single fused kernel. Per block: issue HBM prefetch first; while it's in
// flight, compute the s(mag) table (f32[1025], 4KB) inline and stage the FIR
// taps hi/lo into LDS (coalesced — kills the 32 scattered per-lane global
// loads the frag build used to do). Then wave-private stage (f16 hi/lo) +
// 18-MFMA Toeplitz FIR (3 precision terms) + post-MLP epilogue.
__global__ __launch_bounds__(256, 5) void fused_hammer_mfma(
    const float* __restrict__ xr_g,   const float* __restrict__ xi_g,
    const float* __restrict__ w1_pre, const float* __restrict__ w2_pre,
    const float* __restrict__ wfr,    const float* __restrict__ wfi,
    const float* __restrict__ w1_post,const float* __restrict__ b1_post,
    const float* __restrict__ w2_post,const float* __restrict__ b2_post,
    float* __restrict__ out)
{
    __shared__ __align__(16) _Float16 s_rh[4][NSW];
    __shared__ __align__(16) _Float16 s_rl[4][NSW];
    __shared__ __align__(16) _Float16 s_ih[4][NSW];
    __shared__ __align__(16) _Float16 s_il[4][NSW];
    __shared__ __align__(16) float    s_tab[TBL_N + 1];   // 4100 B
    __shared__ __align__(16) _Float16 s_wrh[32], s_wrl[32], s_wih[32], s_wil[32];

    const int tid    = threadIdx.x;
    const int lane   = tid & 63;
    const int wv     = tid >> 6;
    const int brow   = blockIdx.y;
    const long rowbase = (long)brow * WIDTH;
    const int wstart = blockIdx.x * 2048 + wv * WTILE;

    // ---- 1. issue this wave's slice loads FIRST (branchless clamp) ----
    const int g0 = min(wstart       + 4 * lane, WIDTH - 4);
    const int g1 = min(wstart + 256 + 4 * lane, WIDTH - 4);
    float4 r0 = *(const float4*)(xr_g + rowbase + g0);
    float4 i0 = *(const float4*)(xi_g + rowbase + g0);
    float4 r1 = *(const float4*)(xr_g + rowbase + g1);
    float4 i1 = *(const float4*)(xi_g + rowbase + g1);
    float4 r2, i2;
    if (lane < 12) {
        const int g2 = min(wstart + 512 + 4 * lane, WIDTH - 4);
        r2 = *(const float4*)(xr_g + rowbase + g2);
        i2 = *(const float4*)(xi_g + rowbase + g2);
    }

    // ---- 2. overlap the load latency with table + tap-split setup ----
    {
        float w1v[8], w2v[8];
#pragma unroll
        for (int f = 0; f < 8; ++f) { w1v[f] = w1_pre[f]; w2v[f] = w2_pre[f]; }
        for (int i = tid; i <= TBL_N; i += 256)
            s_tab[i] = s_of_mag((float)i * (1.0f / TBL_SCL), w1v, w2v);
    }
    if (tid < 32) {                       // stage FIR taps hi/lo (coalesced)
        const float wr = wfr[tid], wi = wfi[tid];
        const _Float16 wrh = (_Float16)wr, wih = (_Float16)wi;
        s_wrh[tid] = wrh; s_wrl[tid] = (_Float16)(wr - (float)wrh);
        s_wih[tid] = wih; s_wil[tid] = (_Float16)(wi - (float)wih);
    }

    // ---- post-MLP uniform weights (scalar) ----
    float w1p[8], b1p[8], w2p[8];
#pragma unroll
    for (int f = 0; f < 8; ++f) { w1p[f] = w1_post[f]; b1p[f] = b1_post[f]; w2p[f] = w2_post[f]; }
    const float b2p = b2_post[0];

    __syncthreads();   // s_tab + tap splits visible; only barrier in kernel

    // ---- 3. build Toeplitz A-fragments from LDS taps (no global scatter) ----
    const int jA = lane & 15;
    const int kg = lane >> 4;
    half8 A1r_h, A1r_l, A1mi_h, A1mi_l, A1i_h, A1i_l, A2r_h, A2r_l, A2i_h, A2i_l;
#pragma unroll
    for (int jj = 0; jj < 8; ++jj) {
        const int k  = 8 * kg + jj;
        const int t1 = k - jA;                         // -15..31
        const bool v1 = (t1 >= 0);
        const int x1 = max(t1, 0);
        const _Float16 z = (_Float16)0.f;
        const _Float16 wr1h = v1 ? s_wrh[x1] : z, wr1l = v1 ? s_wrl[x1] : z;
        const _Float16 wi1h = v1 ? s_wih[x1] : z, wi1l = v1 ? s_wil[x1] : z;
        const int t2 = (k < 16) ? (k + 32 - jA) : (k + 16 - jA);   // 17..47
        const bool v2 = (t2 <= 31);
        const int x2 = min(t2, 31);
        const _Float16 wr2h = v2 ? s_wrh[x2] : z, wr2l = v2 ? s_wrl[x2] : z;
        const _Float16 wi2h = v2 ? s_wih[x2] : z, wi2l = v2 ? s_wil[x2] : z;
        A1r_h[jj]  = wr1h;  A1r_l[jj]  = wr1l;
        A1mi_h[jj] = -wi1h; A1mi_l[jj] = -wi1l;
        A1i_h[jj]  = wi1h;  A1i_l[jj]  = wi1l;
        A2r_h[jj]  = (k < 16) ? wr2h : -wi2h;   // zr chunk2: [wr | -wi]
        A2r_l[jj]  = (k < 16) ? wr2l : -wi2l;
        A2i_h[jj]  = (k < 16) ? wi2h : wr2h;    // zi chunk2: [wi |  wr]
        A2i_l[jj]  = (k < 16) ? wi2l : wr2l;
    }

    const bool row_aligned = ((brow & 1) == 0);   // even brow -> 16B-aligned stores

    // stage one float4-pair into strip group p (table lerp + f16 hi/lo split)
#define STAGE4(VR, VI, P)                                                     \
    do {                                                                      \
        const float* vrf = &(VR).x;                                           \
        const float* vif = &(VI).x;                                           \
        half4v rh_, rl_, ih_, il_;                                            \
        _Pragma("unroll")                                                     \
        for (int e = 0; e < 4; ++e) {                                         \
            const float r  = vrf[e], im = vif[e];                             \
            const float sq  = fmaf(r, r, im * im);                            \
            const float mag = __builtin_sqrtf(sq);                            \
            const float t   = fminf(mag * TBL_SCL, (float)TBL_N - 0.001f);    \
            const int   i0  = (int)t;                                         \
            const float frac = t - (float)i0;                                 \
            const float sa = s_tab[i0];                                       \
            const float sb = s_tab[i0 + 1];                                   \
            const float s  = fmaf(frac, sb - sa, sa);                         \
            const float xhr = s * r;                                          \
            const float xhi = s * im;                                         \
            const _Float16 hr = (_Float16)xhr;                                \
            const _Float16 hi = (_Float16)xhi;                                \
            rh_[e] = hr; rl_[e] = (_Float16)(xhr - (float)hr);                \
            ih_[e] = hi; il_[e] = (_Float16)(xhi - (float)hi);                \
        }                                                                     \
        *(half4v*)&s_rh[wv][4 * (P)] = rh_;                                   \
        *(half4v*)&s_rl[wv][4 * (P)] = rl_;                                   \
        *(half4v*)&s_ih[wv][4 * (P)] = ih_;                                   \
        *(half4v*)&s_il[wv][4 * (P)] = il_;                                   \
    } while (0)

    // ---- 4. stage this wave's slice ----
    STAGE4(r0, i0, lane);
    STAGE4(r1, i1, 64 + lane);
    if (lane < 12) STAGE4(r2, i2, 128 + lane);

    // wave-private LDS: own writes complete -> readable, no block barrier
    asm volatile("s_waitcnt lgkmcnt(0)" ::: "memory");

    // ---- 5. MFMA FIR + post-MLP epilogue, 2 tiles of 256 outputs ----
#pragma unroll
    for (int tt = 0; tt < 2; ++tt) {
        const int base_o = 256 * tt;
        const int i1x = base_o + 16 * jA + 8 * kg;           // B1 elements
        const half8 Bxr_h = *(const half8*)&s_rh[wv][i1x];
        const half8 Bxi_h = *(const half8*)&s_ih[wv][i1x];
        const half8 Bxr_l = *(const half8*)&s_rl[wv][i1x];
        const half8 Bxi_l = *(const half8*)&s_il[wv][i1x];
        const int i2x = base_o + 16 * jA + 32 + 8 * (kg & 1); // B2 mixed
        const _Float16* srcH = (kg < 2) ? s_rh[wv] : s_ih[wv];
        const _Float16* srcL = (kg < 2) ? s_rl[wv] : s_il[wv];
        const half8 Bmx_h = *(const half8*)&srcH[i2x];
        const half8 Bmx_l = *(const half8*)&srcL[i2x];

        floatx4 accr = {0.f, 0.f, 0.f, 0.f};
        floatx4 acci = {0.f, 0.f, 0.f, 0.f};
        accr = MFMA16(A1r_h,  Bxr_h, accr);  acci = MFMA16(A1i_h,  Bxr_h, acci);
        accr = MFMA16(A1mi_h, Bxi_h, accr);  acci = MFMA16(A1r_h,  Bxi_h, acci);
        accr = MFMA16(A2r_h,  Bmx_h, accr);  acci = MFMA16(A2i_h,  Bmx_h, acci);
        accr = MFMA16(A1r_h,  Bxr_l, accr);  acci = MFMA16(A1i_h,  Bxr_l, acci);
        accr = MFMA16(A1mi_h, Bxi_l, accr);  acci = MFMA16(A1r_h,  Bxi_l, acci);
        accr = MFMA16(A2r_h,  Bmx_l, accr);  acci = MFMA16(A2i_h,  Bmx_l, acci);
        accr = MFMA16(A1r_l,  Bxr_h, accr);  acci = MFMA16(A1i_l,  Bxr_h, acci);
        accr = MFMA16(A1mi_l, Bxi_h, accr);  acci = MFMA16(A1r_l,  Bxi_h, acci);
        accr = MFMA16(A2r_l,  Bmx_h, accr);  acci = MFMA16(A2i_l,  Bmx_h, acci);

        // epilogue: lane owns 4 CONSECUTIVE outputs obase..obase+3
        const int obase = wstart + base_o + 16 * jA + 4 * kg;
        float ox[8];
#pragma unroll
        for (int r = 0; r < 4; ++r) {
            const float zr  = accr[r], zi = acci[r];
            const float zsq = fmaf(zr, zr, zi * zi);
            const float rs  = (zsq > 0.f) ? __builtin_amdgcn_rsqf(zsq) : 0.f;
            const float zmag = zsq * rs;
            float zm = b2p;
#pragma unroll
            for (int f = 0; f < 8; ++f) {
                const float gfv = fmaf(zmag, w1p[f], b1p[f]);
                zm = fmaf(fmaxf(gfv, 0.f), w2p[f], zm);
            }
            const float t = SCALE_V * zm * rs;
            ox[2 * r]     = (zsq > 0.f) ? t * zr : SCALE_V * zm;
            ox[2 * r + 1] = t * zi;
        }
        float* po = &out[((long)brow * OUTW + obase) * 2];
        if (obase + 3 < OUTW) {
            if (row_aligned) {
                *(float4*)(po)     = make_float4(ox[0], ox[1], ox[2], ox[3]);
                *(float4*)(po + 4) = make_float4(ox[4], ox[5], ox[6], ox[7]);
            } else {
#pragma unroll
                for (int r = 0; r < 4; ++r)
                    *(float2*)(po + 2 * r) = make_float2(ox[2 * r], ox[2 * r + 1]);
            }
        } else {
#pragma unroll
            for (int r = 0; r < 4; ++r)
                if (obase + r < OUTW)
                    *(float2*)(po + 2 * r) = make_float2(ox[2 * r], ox[2 * r + 1]);
        }
    }
#undef STAGE4
}

extern "C" void kernel_launch(void* const* d_in, const int* in_sizes, int n_in,
                              void* d_out, int out_size, void* d_ws, size_t ws_size,
                              hipStream_t stream) {
    dim3 grid(128, 16);             // 2048 outputs/block; 2048 blocks total
    fused_hammer_mfma<<<grid, 256, 0, stream>>>(
        (const float*)d_in[0], (const float*)d_in[1],
        (const float*)d_in[2], (const float*)d_in[3],
        (const float*)d_in[4], (const float*)d_in[5],
        (const float*)d_in[6], (const float*)d_in[7],
        (const float*)d_in[8], (const float*)d_in[9],
        (float*)d_out);
}

// Round 10
// 123.103 us; speedup vs baseline: 1.0191x; 1.0191x over previous
//
#include <hip/hip_runtime.h>

// ===== INSTRUMENTATION PROBE ROUND =====
// R7-best structure, but grid.y doubled (32) with brow = blockIdx.y & 15:
// every output is written twice with identical values (idempotent), so the
// kernel runs ~2x longer and rises above the harness's ~42us poison-fill
// dispatches in the rocprof top-5, finally giving us its counter row.

#define WIDTH  262144
#define OUTW   (WIDTH - 31)         // 262113
#define WTILE  512                  // outputs per slice
#define NSW    560                  // staged elements per slice (512 + 48 halo)
#define SCALE_V 0.17782794100389229f // sqrt(10^(-15/10))
#define LOG2E_X2 2.8853900817779268f // 2*log2(e)

#define TBL_N    1024
#define TBL_MAX  10.0f
#define TBL_SCL  (TBL_N / TBL_MAX)   // 102.4

typedef _Float16 half8  __attribute__((ext_vector_type(8)));
typedef _Float16 half4v __attribute__((ext_vector_type(4)));
typedef float    floatx4 __attribute__((ext_vector_type(4)));

__device__ __forceinline__ float wload(const float* __restrict__ w, int t) {
    return (t >= 0 && t < 32) ? w[t] : 0.0f;
}

#define MFMA16(A, B, C) __builtin_amdgcn_mfma_f32_16x16x32_f16((A), (B), (C), 0, 0, 0)

__device__ __forceinline__ float s_of_mag(float mag, const float* w1, const float* w2) {
    if (mag == 0.0f) {
        float s = 0.f;
#pragma unroll
        for (int f = 0; f < 8; ++f) s = fmaf(w2[f], w1[f], s);   // tanh'(0)=1
        return s;
    }
    float m = 0.f;
#pragma unroll
    for (int f = 0; f < 8; ++f) {
        const float e2 = __builtin_amdgcn_exp2f(LOG2E_X2 * w1[f] * mag);
        const float th = 1.0f - 2.0f * __builtin_amdgcn_rcpf(e2 + 1.0f);
        m = fmaf(w2[f], th, m);
    }
    return m / mag;
}

__global__ void fill_s_table(const float* __restrict__ w1_pre,
                             const float* __restrict__ w2_pre,
                             float2* __restrict__ tbl)
{
    const int i = blockIdx.x * 256 + threadIdx.x;   // 0..1023
    if (i >= TBL_N) return;
    float w1[8], w2[8];
#pragma unroll
    for (int f = 0; f < 8; ++f) { w1[f] = w1_pre[f]; w2[f] = w2_pre[f]; }
    const float m0 = (float)i       * (1.0f / TBL_SCL);
    const float m1 = (float)(i + 1) * (1.0f / TBL_SCL);
    const float s0 = s_of_mag(m0, w1, w2);
    const float s1 = s_of_mag(m1, w1, w2);
    tbl[i] = make_float2(s0, s1 - s0);
}

__global__ __launch_bounds__(256, 4) void fused_hammer_mfma(
    const float* __restrict__ xr_g,   const float* __restrict__ xi_g,
    const float* __restrict__ w1_pre, const float* __restrict__ w2_pre,
    const float* __restrict__ wfr,    const float* __restrict__ wfi,
    const float* __restrict__ w1_post,const float* __restrict__ b1_post,
    const float* __restrict__ w2_post,const float* __restrict__ b2_post,
    const float2* __restrict__ tbl_g,
    float* __restrict__ out)
{
    __shared__ __align__(16) _Float16 s_rh[4][NSW];
    __shared__ __align__(16) _Float16 s_rl[4][NSW];
    __shared__ __align__(16) _Float16 s_ih[4][NSW];
    __shared__ __align__(16) _Float16 s_il[4][NSW];
    __shared__ __align__(16) float2   s_tab[TBL_N];

    const int tid    = threadIdx.x;
    const int lane   = tid & 63;
    const int wv     = tid >> 6;
    const int brow   = blockIdx.y & 15;    // PROBE: two grid.y slots per row
    const long rowbase = (long)brow * WIDTH;
    const int wbase  = blockIdx.x * 4096 + wv * 1024;  // wave's first slice offset

    // ---- prefetch slice 0 (2 float4-pairs per lane; branchless clamp) ----
    const int g0 = min(wbase       + 4 * lane, WIDTH - 4);
    const int g1 = min(wbase + 256 + 4 * lane, WIDTH - 4);
    float4 p_r0 = *(const float4*)(xr_g + rowbase + g0);
    float4 p_i0 = *(const float4*)(xi_g + rowbase + g0);
    float4 p_r1 = *(const float4*)(xr_g + rowbase + g1);
    float4 p_i1 = *(const float4*)(xi_g + rowbase + g1);

    // ---- load s-table into LDS (1024 float2 = 512 float4; 2 per thread) ----
    {
        const float4* src = (const float4*)tbl_g;
#pragma unroll
        for (int q = 0; q < 2; ++q) {
            const int idx = 2 * tid + q;            // 0..511
            ((float4*)s_tab)[idx] = src[idx];
        }
    }

    // ---- post-MLP uniform weights ----
    float w1p[8], b1p[8], w2p[8];
#pragma unroll
    for (int f = 0; f < 8; ++f) { w1p[f] = w1_post[f]; b1p[f] = b1_post[f]; w2p[f] = w2_post[f]; }
    const float b2p = b2_post[0];

    // ---- build Toeplitz weight fragments (hi/lo f16), once per lane ----
    const int jA = lane & 15;
    const int kg = lane >> 4;
    half8 A1r_h, A1r_l, A1mi_h, A1mi_l, A1i_h, A1i_l, A2r_h, A2r_l, A2i_h, A2i_l;
#pragma unroll
    for (int jj = 0; jj < 8; ++jj) {
        const int k  = 8 * kg + jj;
        const int t1 = k - jA;
        const float wr1 = wload(wfr, t1);
        const float wi1 = wload(wfi, t1);
        const int t2 = (k < 16) ? (k + 32 - jA) : (k + 16 - jA);
        const float wr2 = wload(wfr, t2);
        const float wi2 = wload(wfi, t2);
        const float a2r = (k < 16) ? wr2 : -wi2;   // zr second chunk: [wr | -wi]
        const float a2i = (k < 16) ? wi2 : wr2;    // zi second chunk: [wi |  wr]
        _Float16 h;
        h = (_Float16)wr1;   A1r_h[jj]  = h; A1r_l[jj]  = (_Float16)(wr1 - (float)h);
        h = (_Float16)(-wi1);A1mi_h[jj] = h; A1mi_l[jj] = (_Float16)(-wi1 - (float)h);
        h = (_Float16)wi1;   A1i_h[jj]  = h; A1i_l[jj]  = (_Float16)(wi1 - (float)h);
        h = (_Float16)a2r;   A2r_h[jj]  = h; A2r_l[jj]  = (_Float16)(a2r - (float)h);
        h = (_Float16)a2i;   A2i_h[jj]  = h; A2i_l[jj]  = (_Float16)(a2i - (float)h);
    }

    __syncthreads();   // s_tab visible to all waves; only barrier in the kernel

    const bool row_aligned = ((brow & 1) == 0);   // even brow -> 16B-aligned stores

#define STAGE4(VR, VI, P)                                                     \
    do {                                                                      \
        const float* vrf = &(VR).x;                                           \
        const float* vif = &(VI).x;                                           \
        half4v rh_, rl_, ih_, il_;                                            \
        _Pragma("unroll")                                                     \
        for (int e = 0; e < 4; ++e) {                                         \
            const float r  = vrf[e], im = vif[e];                             \
            const float sq  = fmaf(r, r, im * im);                            \
            const float mag = __builtin_sqrtf(sq);                            \
            const float t   = fminf(mag * TBL_SCL, (float)(TBL_N - 2) + 0.999f); \
            const int   i0  = (int)t;                                         \
            const float frac = t - (float)i0;                                 \
            const float2 en = s_tab[i0];                                      \
            const float s   = fmaf(frac, en.y, en.x);                         \
            const float xhr = s * r;                                          \
            const float xhi = s * im;                                         \
            const _Float16 hr = (_Float16)xhr;                                \
            const _Float16 hi = (_Float16)xhi;                                \
            rh_[e] = hr; rl_[e] = (_Float16)(xhr - (float)hr);                \
            ih_[e] = hi; il_[e] = (_Float16)(xhi - (float)hi);                \
        }                                                                     \
        *(half4v*)&s_rh[wv][4 * (P)] = rh_;                                   \
        *(half4v*)&s_rl[wv][4 * (P)] = rl_;                                   \
        *(half4v*)&s_ih[wv][4 * (P)] = ih_;                                   \
        *(half4v*)&s_il[wv][4 * (P)] = il_;                                   \
    } while (0)

#pragma unroll
    for (int q = 0; q < 2; ++q) {
        const int wstart = wbase + q * WTILE;

        // halo pair (strip groups 128..139, lanes 0..11 only)
        float4 h_r, h_i;
        if (lane < 12) {
            const int g2 = min(wstart + 512 + 4 * lane, WIDTH - 4);
            h_r = *(const float4*)(xr_g + rowbase + g2);
            h_i = *(const float4*)(xi_g + rowbase + g2);
        }

        STAGE4(p_r0, p_i0, lane);
        STAGE4(p_r1, p_i1, 64 + lane);

        if (q == 0) {   // prefetch slice 1 while slice 0 computes below
            const int n0 = min(wbase + 512       + 4 * lane, WIDTH - 4);
            const int n1 = min(wbase + 512 + 256 + 4 * lane, WIDTH - 4);
            p_r0 = *(const float4*)(xr_g + rowbase + n0);
            p_i0 = *(const float4*)(xi_g + rowbase + n0);
            p_r1 = *(const float4*)(xr_g + rowbase + n1);
            p_i1 = *(const float4*)(xi_g + rowbase + n1);
        }

        if (lane < 12) STAGE4(h_r, h_i, 128 + lane);

        // wave-private LDS: own writes complete -> readable, no block barrier
        asm volatile("s_waitcnt lgkmcnt(0)" ::: "memory");

        // ---- MFMA FIR + post-MLP epilogue, 2 tiles of 256 outputs ----
#pragma unroll
        for (int tt = 0; tt < 2; ++tt) {
            const int base_o = 256 * tt;
            const int i1 = base_o + 16 * jA + 8 * kg;          // B1 elements
            const half8 Bxr_h = *(const half8*)&s_rh[wv][i1];
            const half8 Bxi_h = *(const half8*)&s_ih[wv][i1];
            const half8 Bxr_l = *(const half8*)&s_rl[wv][i1];
            const half8 Bxi_l = *(const half8*)&s_il[wv][i1];
            const int i2 = base_o + 16 * jA + 32 + 8 * (kg & 1); // B2 mixed
            const _Float16* srcH = (kg < 2) ? s_rh[wv] : s_ih[wv];
            const _Float16* srcL = (kg < 2) ? s_rl[wv] : s_il[wv];
            const half8 Bmx_h = *(const half8*)&srcH[i2];
            const half8 Bmx_l = *(const half8*)&srcL[i2];

            floatx4 accr = {0.f, 0.f, 0.f, 0.f};
            floatx4 acci = {0.f, 0.f, 0.f, 0.f};
            accr = MFMA16(A1r_h,  Bxr_h, accr);  acci = MFMA16(A1i_h,  Bxr_h, acci);
            accr = MFMA16(A1mi_h, Bxi_h, accr);  acci = MFMA16(A1r_h,  Bxi_h, acci);
            accr = MFMA16(A2r_h,  Bmx_h, accr);  acci = MFMA16(A2i_h,  Bmx_h, acci);
            accr = MFMA16(A1r_h,  Bxr_l, accr);  acci = MFMA16(A1i_h,  Bxr_l, acci);
            accr = MFMA16(A1mi_h, Bxi_l, accr);  acci = MFMA16(A1r_h,  Bxi_l, acci);
            accr = MFMA16(A2r_h,  Bmx_l, accr);  acci = MFMA16(A2i_h,  Bmx_l, acci);
            accr = MFMA16(A1r_l,  Bxr_h, accr);  acci = MFMA16(A1i_l,  Bxr_h, acci);
            accr = MFMA16(A1mi_l, Bxi_h, accr);  acci = MFMA16(A1r_l,  Bxi_h, acci);
            accr = MFMA16(A2r_l,  Bmx_h, accr);  acci = MFMA16(A2i_l,  Bmx_h, acci);

            // epilogue: lane owns 4 CONSECUTIVE outputs obase..obase+3
            const int obase = wstart + base_o + 16 * jA + 4 * kg;
            float ox[8];
#pragma unroll
            for (int r = 0; r < 4; ++r) {
                const float zr  = accr[r], zi = acci[r];
                const float zsq = fmaf(zr, zr, zi * zi);
                const float rs  = (zsq > 0.f) ? __builtin_amdgcn_rsqf(zsq) : 0.f;
                const float zmag = zsq * rs;
                float zm = b2p;
#pragma unroll
                for (int f = 0; f < 8; ++f) {
                    const float gfv = fmaf(zmag, w1p[f], b1p[f]);
                    zm = fmaf(fmaxf(gfv, 0.f), w2p[f], zm);
                }
                const float t = SCALE_V * zm * rs;
                ox[2 * r]     = (zsq > 0.f) ? t * zr : SCALE_V * zm;
                ox[2 * r + 1] = t * zi;
            }
            float* po = &out[((long)brow * OUTW + obase) * 2];
            if (obase + 3 < OUTW) {
                if (row_aligned) {
                    *(float4*)(po)     = make_float4(ox[0], ox[1], ox[2], ox[3]);
                    *(float4*)(po + 4) = make_float4(ox[4], ox[5], ox[6], ox[7]);
                } else {
#pragma unroll
                    for (int r = 0; r < 4; ++r)
                        *(float2*)(po + 2 * r) = make_float2(ox[2 * r], ox[2 * r + 1]);
                }
            } else {
#pragma unroll
                for (int r = 0; r < 4; ++r)
                    if (obase + r < OUTW)
                        *(float2*)(po + 2 * r) = make_float2(ox[2 * r], ox[2 * r + 1]);
            }
        }
    }
#undef STAGE4
}

extern "C" void kernel_launch(void* const* d_in, const int* in_sizes, int n_in,
                              void* d_out, int out_size, void* d_ws, size_t ws_size,
                              hipStream_t stream) {
    float2* tbl = (float2*)d_ws;    // 8 KB of workspace
    fill_s_table<<<dim3((TBL_N + 255) / 256), 256, 0, stream>>>(
        (const float*)d_in[2], (const float*)d_in[3], tbl);

    dim3 grid(64, 32);              // PROBE: 2x grid.y, each output written twice
    fused_hammer_mfma<<<grid, 256, 0, stream>>>(
        (const float*)d_in[0], (const float*)d_in[1],
        (const float*)d_in[2], (const float*)d_in[3],
        (const float*)d_in[4], (const float*)d_in[5],
        (const float*)d_in[6], (const float*)d_in[7],
        (const float*)d_in[8], (const float*)d_in[9],
        tbl,
        (float*)d_out);
}